// Round 5
// baseline (387.872 us; speedup 1.0000x reference)
//
#include <hip/hip_runtime.h>

// ParametrisedPooling: out[t] = sum_k w[n,k] * x_in[idx[n,k], :], n = indices_target[t]
//
// R5: two-phase L3-chunked gather WITHOUT cooperative launch.
// x_in (335.6 MB) > L3 (256 MB) and gathers are uniform-random -> only
// probabilistic reuse capture. Split x_in into two 168 MB halves; phase 0
// accumulates only neighbors with src < CHUNK, phase 1 the rest. Accumulators
// stay in registers across the boundary, so NO data crosses the grid barrier
// -> the barrier is purely advisory for L3 locality. We use a best-effort
// software barrier (atomic counter in d_ws, bounded spin): if co-residency or
// the barrier ever fails, blocks proceed early -- slower, never wrong.

constexpr int N_SRC  = 655362;
constexpr int N6     = 163830;
constexpr int N7     = 12;
constexpr int N_OUT  = N6 + N7;          // 163842
constexpr int D      = 128;
constexpr int CHUNK  = N_SRC / 2 + 1;    // 327682: halves of ~167.8 MB each

constexpr int BLOCK  = 256;
constexpr int GRID   = 1024;             // 4 blocks/CU x 256 CU, all resident at t=0
constexpr int GROUPS_PER_BLOCK = BLOCK / 32;              // 8 half-wave groups
constexpr int NGROUPS = GRID * GROUPS_PER_BLOCK;          // 8192
constexpr int ROWS    = (N_OUT + NGROUPS - 1) / NGROUPS;  // 21 (most groups do 20)

template <int PHASE>
__device__ __forceinline__ void accum_row(
    float4& a, int row, int lane,
    const float* __restrict__ x_in,
    const float* __restrict__ w6, const float* __restrict__ w7,
    const int* __restrict__ idx6, const int* __restrict__ idx7,
    const int* __restrict__ tgt)
{
    const int n = tgt[row];
    const int*   ip;
    const float* wp;
    int deg;
    if (n < N6) {
        ip = idx6 + (size_t)n * 6; wp = w6 + (size_t)n * 6; deg = 6;
    } else {
        const int m = n - N6;
        ip = idx7 + (size_t)m * 7; wp = w7 + (size_t)m * 7; deg = 7;
    }
#pragma unroll
    for (int k = 0; k < 7; ++k) {
        if (k < deg) {
            const int s = ip[k];
            const bool sel = (PHASE == 0) ? (s < CHUNK) : (s >= CHUNK);
            if (sel) {
                const float w  = wp[k];
                const float4 v = *reinterpret_cast<const float4*>(
                    x_in + (size_t)s * D + (size_t)lane * 4);
                a.x += w * v.x;
                a.y += w * v.y;
                a.z += w * v.z;
                a.w += w * v.w;
            }
        }
    }
}

__global__ __launch_bounds__(BLOCK, 4) void pool2_kernel(
    const float* __restrict__ x_in,
    const float* __restrict__ w6,
    const float* __restrict__ w7,
    const int*   __restrict__ idx6,
    const int*   __restrict__ idx7,
    const int*   __restrict__ tgt,
    float*       __restrict__ out,
    unsigned int* barrier_cnt)           // zeroed via hipMemsetAsync each call
{
    const int g    = blockIdx.x * GROUPS_PER_BLOCK + (threadIdx.x >> 5);
    const int lane = threadIdx.x & 31;

    float4 acc[ROWS];
#pragma unroll
    for (int r = 0; r < ROWS; ++r) acc[r] = make_float4(0.f, 0.f, 0.f, 0.f);

    // Phase 0: gather rows in the lower half of x_in only.
#pragma unroll
    for (int r = 0; r < ROWS; ++r) {
        const int row = g + r * NGROUPS;
        if (row < N_OUT)
            accum_row<0>(acc[r], row, lane, x_in, w6, w7, idx6, idx7, tgt);
    }

    // Best-effort grid barrier: advisory only (no data crosses it).
    if (barrier_cnt != nullptr) {
        if (threadIdx.x == 0) {
            __hip_atomic_fetch_add(barrier_cnt, 1u,
                                   __ATOMIC_ACQ_REL, __HIP_MEMORY_SCOPE_AGENT);
            int spins = 0;
            while (__hip_atomic_load(barrier_cnt, __ATOMIC_ACQUIRE,
                                     __HIP_MEMORY_SCOPE_AGENT) < (unsigned)GRID
                   && spins < 65536) {
                __builtin_amdgcn_s_sleep(2);
                ++spins;
            }
        }
        __syncthreads();
    }

    // Phase 1: gather rows in the upper half, then store the finished row.
#pragma unroll
    for (int r = 0; r < ROWS; ++r) {
        const int row = g + r * NGROUPS;
        if (row < N_OUT) {
            accum_row<1>(acc[r], row, lane, x_in, w6, w7, idx6, idx7, tgt);
            float* op = out + (size_t)row * D + (size_t)lane * 4;
            __builtin_nontemporal_store(acc[r].x, op + 0);
            __builtin_nontemporal_store(acc[r].y, op + 1);
            __builtin_nontemporal_store(acc[r].z, op + 2);
            __builtin_nontemporal_store(acc[r].w, op + 3);
        }
    }
}

extern "C" void kernel_launch(void* const* d_in, const int* in_sizes, int n_in,
                              void* d_out, int out_size, void* d_ws, size_t ws_size,
                              hipStream_t stream) {
    const float* x_in = (const float*)d_in[0];
    const float* w6   = (const float*)d_in[1];
    const float* w7   = (const float*)d_in[2];
    const int*   idx6 = (const int*)d_in[3];
    const int*   idx7 = (const int*)d_in[4];
    const int*   tgt  = (const int*)d_in[5];
    float*       out  = (float*)d_out;

    unsigned int* barrier_cnt = nullptr;
    if (ws_size >= sizeof(unsigned int)) {
        barrier_cnt = (unsigned int*)d_ws;
        hipMemsetAsync(barrier_cnt, 0, sizeof(unsigned int), stream);
    }

    pool2_kernel<<<GRID, BLOCK, 0, stream>>>(x_in, w6, w7, idx6, idx7, tgt,
                                             out, barrier_cnt);
}